// Round 14
// baseline (181.113 us; speedup 1.0000x reference)
//
#include <hip/hip_runtime.h>
#include <stdint.h>

typedef __attribute__((ext_vector_type(8))) short short8;
typedef __attribute__((ext_vector_type(4))) short s16x4;
typedef __attribute__((ext_vector_type(4))) float f32x4;
typedef __attribute__((ext_vector_type(16))) float f32x16;

#define DEVI __device__ __forceinline__

#if __has_builtin(__builtin_amdgcn_mfma_f32_16x16x16_bf16)
#define MFMA16(a, b, c) __builtin_amdgcn_mfma_f32_16x16x16_bf16(a, b, c, 0, 0, 0)
#else
#define MFMA16(a, b, c) __builtin_amdgcn_mfma_f32_16x16x16bf16_1k(a, b, c, 0, 0, 0)
#endif
#define MFMA32(a, b, c) __builtin_amdgcn_mfma_f32_32x32x16_bf16(a, b, c, 0, 0, 0)

DEVI unsigned short f2bf(float f) {
  union { float f; uint32_t u; } v; v.f = f;
  return (unsigned short)((v.u + 0x7fffu + ((v.u >> 16) & 1u)) >> 16);
}

DEVI float bf2f(uint32_t hi16) {
  union { uint32_t u; float f; } v; v.u = hi16;
  return v.f;
}

DEVI uint32_t pkbf(float a, float b) {  // fast RTN pack (positive values)
  union { float f; uint32_t u; } x, y; x.f = a; y.f = b;
  return ((x.u + 0x8000u) >> 16) | (((y.u + 0x8000u) >> 16) << 16);
}

DEVI void gload_lds16(const void* g, void* l) {
  __builtin_amdgcn_global_load_lds(
      (const __attribute__((address_space(1))) uint32_t*)g,
      (__attribute__((address_space(3))) uint32_t*)l, 16, 0, 0);
}

// ---------------- K1: xpT = (x + pe) transposed to [b*1024+n][256], f32 + bf16 ----------------
__global__ __launch_bounds__(256) void k_xpt(const float* __restrict__ x,
                                             const float* __restrict__ T,
                                             unsigned short* __restrict__ xpt_bf,
                                             float* __restrict__ xpt_f) {
  __shared__ __align__(16) float tile[32][36];
  const int b = blockIdx.z, c0 = blockIdx.x * 32, n0 = blockIdx.y * 32;
  const int t = threadIdx.x;
  {
    const int cl = t >> 3, ng = (t & 7) * 4;
    const int c = c0 + cl;
    float4 v = *(const float4*)(x + ((size_t)b * 256 + c) * 1024 + n0 + ng);
    float p0, p1, p2, p3;
    if (c < 128) {
      p0 = T[c * 32 + ng + 0]; p1 = T[c * 32 + ng + 1];
      p2 = T[c * 32 + ng + 2]; p3 = T[c * 32 + ng + 3];
    } else {
      p0 = p1 = p2 = p3 = T[c * 32 + (n0 >> 5)];
    }
    tile[ng + 0][cl] = v.x + p0;
    tile[ng + 1][cl] = v.y + p1;
    tile[ng + 2][cl] = v.z + p2;
    tile[ng + 3][cl] = v.w + p3;
  }
  __syncthreads();
  {
    const int nl = t >> 3, cg = (t & 7) * 4;
    float o0 = tile[nl][cg + 0], o1 = tile[nl][cg + 1];
    float o2 = tile[nl][cg + 2], o3 = tile[nl][cg + 3];
    size_t row = (size_t)b * 1024 + n0 + nl;
    *(float4*)(xpt_f + row * 256 + c0 + cg) = make_float4(o0, o1, o2, o3);
    uint32_t lo = (uint32_t)f2bf(o0) | ((uint32_t)f2bf(o1) << 16);
    uint32_t hi = (uint32_t)f2bf(o2) | ((uint32_t)f2bf(o3) << 16);
    *(uint2*)(xpt_bf + row * 256 + c0 + cg) = make_uint2(lo, hi);
  }
}

// ---------------- K2: all preprocessing in one kernel (packs + pe table + zero page) ------------
__global__ void k_prep(const float* __restrict__ Wk, const float* __restrict__ Wq,
                       const float* __restrict__ Wv, const float* __restrict__ bk,
                       const float* __restrict__ bq, const float* __restrict__ bv,
                       const float* __restrict__ Wproj, const float* __restrict__ W1,
                       const float* __restrict__ W2, unsigned short* __restrict__ Wpack,
                       float* __restrict__ bias_kqv, unsigned short* __restrict__ WprojP,
                       unsigned short* __restrict__ W1b, unsigned short* __restrict__ W2b,
                       float* __restrict__ T, float* __restrict__ zp) {
  int bid = blockIdx.x;
  if (bid < 13824) {
    int i = bid * 256 + threadIdx.x;
    if (i >= 1536 * 2304) return;
    int o = i / 2304, kn = i % 2304;
    int ci = kn & 255, khw = kn >> 8;
    const float* src = (o < 512) ? Wk : ((o < 1024) ? Wq : Wv);
    int oo = o & 511;
    Wpack[i] = f2bf(src[((size_t)oo * 256 + ci) * 9 + khw]);
  } else if (bid < 14336) {
    int i = (bid - 13824) * 256 + threadIdx.x;  // [0, 131072)
    if (i < 1536)
      bias_kqv[i] = (i < 512) ? bk[i] : ((i < 1024) ? bq[i - 512] : bv[i - 1024]);
    {
      int j = i >> 9, f = i & 511;
      int h = f >> 6, c = f & 63;
      unsigned short v = f2bf(Wproj[(size_t)j * 512 + c * 8 + h]);
      WprojP[(size_t)j * 1024 + f] = v;        // K-chunk 0
      WprojP[(size_t)j * 1024 + 512 + f] = v;  // K-chunk 1 (duplicated: O = O0 + O1)
    }
    if (i < 65536) {
      W1b[i] = f2bf(W1[i]);
      W2b[i] = f2bf(W2[i]);
    }
  } else {
    int c = threadIdx.x;
    zp[c] = 0.0f;
    int idx = ((c >= 128) ? c - 128 : c) >> 1;
    float freq = expf(-(float)idx * (logf(10000.0f) / 64.0f));
    for (int p = 0; p < 32; ++p) {
      float ang = (float)p * freq;
      T[c * 32 + p] = (c & 1) ? cosf(ang) : sinf(ang);
    }
  }
}

// ---------------- merged conv GEMM v5: 32x32x16 MFMA, kqv[8192][1536] ----------------
// Tile 128m x 192n, wave tile 64x96 = 2x3 blocks of 32x32. 24 MFMA + 20 ds_read_b128
// per K-step (was 48 + 20 with 16x16x32). Same 2-barrier counted-vmcnt(10) pipeline.
// C/D map (HW-verified m74/m101): col = lane&31, row = (reg&3) + 8*(reg>>2) + 4*(lane>>5).
__global__ __launch_bounds__(256, 2) void k_gemm_conv(const unsigned short* __restrict__ xpt,
                                                      const unsigned short* __restrict__ Wp,
                                                      unsigned short* __restrict__ kqv,
                                                      const float* __restrict__ bias,
                                                      const char* __restrict__ zp) {
  __shared__ __align__(16) unsigned short As[2][128 * 64];  // 32KB
  __shared__ __align__(16) unsigned short Bs[2][192 * 64];  // 48KB
  const int tid = threadIdx.x, l = tid & 63, w = tid >> 6;
  const int wm = w >> 1, wn = w & 1;
  const int l31 = l & 31, lh = l >> 5;
  const int id = blockIdx.x + (blockIdx.y << 6);
  const int nid = ((id & 7) << 6) + (id >> 3);   // XCD-contiguous remap (512 = 8*64)
  const int m0 = (nid & 63) * 128, n0 = (nid >> 6) * 192;
  const int swz = (l & 7) ^ (l >> 3);

  const char* pAbase[4];
#pragma unroll
  for (int j = 0; j < 4; ++j) {
    int r = m0 + (w * 4 + j) * 8 + (l >> 3);
    pAbase[j] = (const char*)xpt + ((size_t)r * 256 + swz * 8) * 2;
  }
  const char* pB0 = (const char*)Wp +
                    ((size_t)(n0 + w * 48 + (l >> 3)) * 2304 + swz * 8) * 2;

  f32x16 acc[2][3] = {};
  int vmask = 0;
  int aoff = 0;

  auto setTap = [&](int tap) {
    int d3 = (tap * 11) >> 5;  // tap/3
    int dy = d3 - 1, dx = tap - d3 * 3 - 1;
    aoff = (dy * 32 + dx) * 512;
    int m = 0;
#pragma unroll
    for (int j = 0; j < 4; ++j) {
      int r = m0 + (w * 4 + j) * 8 + (l >> 3);
      int y = ((r >> 5) & 31) + dy;
      int x = (r & 31) + dx;
      if (((unsigned)y < 32u) && ((unsigned)x < 32u)) m |= (1 << j);
    }
    vmask = m;
  };

  auto STAGE = [&](int buf, int kb) {
#pragma unroll
    for (int j = 0; j < 4; ++j) {
      const char* a = (vmask & (1 << j)) ? (pAbase[j] + aoff) : zp;
      gload_lds16(a, (char*)As + buf * 16384 + (w * 4 + j) * 1024);
    }
#pragma unroll
    for (int j = 0; j < 6; ++j) {
      gload_lds16(pB0 + j * 36864 + kb, (char*)Bs + buf * 24576 + (w * 6 + j) * 1024);
    }
  };

  auto COMPUTE = [&](int buf) {
    const char* Ab2 = (const char*)As + buf * 16384;
    const char* Bb2 = (const char*)Bs + buf * 24576;
    __builtin_amdgcn_s_setprio(1);
#pragma unroll
    for (int kk = 0; kk < 4; ++kk) {
      short8 af[2], bfr[3];
#pragma unroll
      for (int fm = 0; fm < 2; ++fm) {
        int row = wm * 64 + fm * 32 + l31;
        af[fm] = *(const short8*)(Ab2 + row * 128 + (((kk * 2 + lh) ^ (row & 7)) * 16));
      }
#pragma unroll
      for (int fn = 0; fn < 3; ++fn) {
        int row = wn * 96 + fn * 32 + l31;
        bfr[fn] = *(const short8*)(Bb2 + row * 128 + (((kk * 2 + lh) ^ (row & 7)) * 16));
      }
#pragma unroll
      for (int fm = 0; fm < 2; ++fm)
#pragma unroll
        for (int fn = 0; fn < 3; ++fn)
          acc[fm][fn] = MFMA32(af[fm], bfr[fn], acc[fm][fn]);
    }
    __builtin_amdgcn_s_setprio(0);
  };

  setTap(0);
  STAGE(0, 0);
  aoff += 128;
  int kb = 128;
  for (int s = 0; s < 36; ++s) {
    const int buf = s & 1;
    if (s < 35) {
      if (((s + 1) & 3) == 0) setTap((s + 1) >> 2);
      STAGE(buf ^ 1, kb);
      kb += 128;
      aoff += 128;
      asm volatile("s_waitcnt vmcnt(10)" ::: "memory");
    } else {
      asm volatile("s_waitcnt vmcnt(0)" ::: "memory");
    }
    __builtin_amdgcn_s_barrier();
    __builtin_amdgcn_sched_barrier(0);
    COMPUTE(buf);
    asm volatile("s_waitcnt lgkmcnt(0)" ::: "memory");
    __builtin_amdgcn_s_barrier();
    __builtin_amdgcn_sched_barrier(0);
  }

  // epilogue: C map col = l&31, row = (reg&3) + 8*(reg>>2) + 4*(l>>5)
#pragma unroll
  for (int fm = 0; fm < 2; ++fm)
#pragma unroll
    for (int fn = 0; fn < 3; ++fn) {
      int col = n0 + wn * 96 + fn * 32 + l31;
      float bb = bias[col];
#pragma unroll
      for (int r = 0; r < 16; ++r) {
        int row = m0 + wm * 64 + fm * 32 + (r & 3) + 8 * (r >> 2) + 4 * lh;
        kqv[(size_t)row * 1536 + col] = f2bf(acc[fm][fn][r] + bb);
      }
    }
}

// ---------------- K5: fused attention v8.1 — tr_read issue hoisted over softmax-total ----------
__global__ __launch_bounds__(512, 4) void k_attn(const unsigned short* __restrict__ kqv,
                                                 unsigned short* __restrict__ part) {
  __shared__ __align__(16) unsigned short Qs[16][512];   // 16KB
  __shared__ __align__(16) char VsRaw[2][32 * 544];      // 34KB
  __shared__ __align__(16) float sums[4][2][64][4];      // 8KB
  const int tid = threadIdx.x, l = tid & 63, w = tid >> 6;
  const int g = l >> 4, ln = l & 15;
  const int nt = w & 1, hg = w >> 1;
  const int id = blockIdx.x;
  const int b = id & 7, ng = (id >> 3) & 31, ch = id >> 8;
  const int n0 = ng * 32 + nt * 16;
  const int m_base = ch * 512;
  const size_t rowBase = (size_t)b * 1024;
  const float SC = 1.0f / 1024.0f;

  short8 ak[2][2];
#pragma unroll
  for (int hl = 0; hl < 2; ++hl)
#pragma unroll
    for (int kk = 0; kk < 2; ++kk)
      ak[hl][kk] = *(const short8*)&kqv[(rowBase + n0 + ln) * 1536 +
                                        (hg * 2 + hl) * 64 + kk * 32 + g * 8];

  f32x4 acc[2][4] = {};

  const int r0 = w * 2, r1 = w * 2 + 1;
  const char* pRow = (const char*)kqv +
                     (size_t)(rowBase + m_base + r0) * 3072 + 1024 + (size_t)l * 16;
  uint4 q0, q1, v0, v1;

  auto LOADREGS = [&]() {
    q0 = *(const uint4*)pRow;
    v0 = *(const uint4*)(pRow + 1024);
    q1 = *(const uint4*)(pRow + 3072);
    v1 = *(const uint4*)(pRow + 4096);
    pRow += 49152;
  };
  char* const dQ0 = (char*)Qs + r0 * 1024 + ((l ^ (r0 & 7)) * 16);
  char* const dQ1 = (char*)Qs + r1 * 1024 + ((l ^ (r1 & 7)) * 16);
  const uint32_t vOff = (uint32_t)(l >> 1) * 544 + (uint32_t)(l & 1) * 16;
  auto DSW = [&](int vbuf) {
    *(uint4*)dQ0 = q0;
    *(uint4*)dQ1 = q1;
    char* vb = VsRaw[vbuf];
    *(uint4*)(vb + vOff + r0 * 32) = v0;
    *(uint4*)(vb + vOff + r1 * 32) = v1;
  };

  LOADREGS();
  asm volatile("s_waitcnt vmcnt(0)" ::: "memory");
  DSW(0);
  asm volatile("s_waitcnt lgkmcnt(0)" ::: "memory");
  __builtin_amdgcn_s_barrier();
  __builtin_amdgcn_sched_barrier(0);

  for (int s = 0; s < 32; ++s) {
    const int buf = s & 1;
    if (s < 31) LOADREGS();

    f32x4 sv[2] = {};
    __builtin_amdgcn_s_setprio(1);
#pragma unroll
    for (int kk = 0; kk < 2; ++kk)
#pragma unroll
      for (int hl = 0; hl < 2; ++hl) {
        int chq = (hg * 2 + hl) * 8 + kk * 4 + g;
        short8 qa = *(const short8*)((const char*)Qs + ln * 1024 +
                                     ((chq ^ (ln & 7)) * 16));
        sv[hl] = __builtin_amdgcn_mfma_f32_16x16x32_bf16(qa, ak[hl][kk], sv[hl], 0, 0, 0);
      }
    __builtin_amdgcn_s_setprio(0);

    f32x4 e0, e1, ps;
#pragma unroll
    for (int j = 0; j < 4; ++j) {
      e0[j] = __expf(sv[0][j] * SC);
      e1[j] = __expf(sv[1][j] * SC);
      ps[j] = e0[j] + e1[j];
    }
    *(f32x4*)&sums[hg][nt][l][0] = ps;
    asm volatile("s_waitcnt lgkmcnt(0)" ::: "memory");
    __builtin_amdgcn_s_barrier();  // B3: sums visible
    __builtin_amdgcn_sched_barrier(0);

    const uint32_t vsB = (uint32_t)(uintptr_t)VsRaw[buf] + l * 8;
    s16x4 vf[8];
#pragma unroll
    for (int hl = 0; hl < 2; ++hl) {
      uint32_t ah = vsB + (hg * 2 + hl) * 2176;
      asm volatile("ds_read_b64_tr_b16 %0, %1" : "=v"(vf[hl * 4 + 0]) : "v"(ah));
      asm volatile("ds_read_b64_tr_b16 %0, %1 offset:544" : "=v"(vf[hl * 4 + 1]) : "v"(ah));
      asm volatile("ds_read_b64_tr_b16 %0, %1 offset:1088" : "=v"(vf[hl * 4 + 2]) : "v"(ah));
      asm volatile("ds_read_b64_tr_b16 %0, %1 offset:1632" : "=v"(vf[hl * 4 + 3]) : "v"(ah));
    }

    f32x4 tot = ps;
#pragma unroll
    for (int d = 1; d < 4; ++d) {
      f32x4 o = *(const f32x4*)&sums[(hg + d) & 3][nt][l][0];
      tot[0] += o[0]; tot[1] += o[1]; tot[2] += o[2]; tot[3] += o[3];
    }
    f32x4 inv;
#pragma unroll
    for (int j = 0; j < 4; ++j) inv[j] = __builtin_amdgcn_rcpf(tot[j]);

    asm volatile("s_waitcnt lgkmcnt(0)" ::: "memory");
    __builtin_amdgcn_sched_barrier(0);
    union { uint32_t u[2]; s16x4 v4; } pc0, pc1;
    pc0.u[0] = pkbf(e0[0] * inv[0], e0[1] * inv[1]);
    pc0.u[1] = pkbf(e0[2] * inv[2], e0[3] * inv[3]);
    pc1.u[0] = pkbf(e1[0] * inv[0], e1[1] * inv[1]);
    pc1.u[1] = pkbf(e1[2] * inv[2], e1[3] * inv[3]);
    __builtin_amdgcn_s_setprio(1);
#pragma unroll
    for (int cf = 0; cf < 4; ++cf) {
      acc[0][cf] = MFMA16(vf[cf], pc0.v4, acc[0][cf]);
      acc[1][cf] = MFMA16(vf[4 + cf], pc1.v4, acc[1][cf]);
    }
    __builtin_amdgcn_s_setprio(0);

    if (s < 31) {
      asm volatile("s_waitcnt vmcnt(0)" ::: "memory");
      DSW(buf ^ 1);
    }
    asm volatile("s_waitcnt lgkmcnt(0)" ::: "memory");
    __builtin_amdgcn_s_barrier();  // B1
    __builtin_amdgcn_sched_barrier(0);
  }

  const size_t outBase = (size_t)ch * 8192 * 512 + (rowBase + n0 + ln) * 512;
#pragma unroll
  for (int hl = 0; hl < 2; ++hl)
#pragma unroll
    for (int cf = 0; cf < 4; ++cf)
#pragma unroll
      for (int r2 = 0; r2 < 2; ++r2) {
        int c = (hg * 2 + hl) * 64 + cf * 16 + g * 4 + r2 * 2;
        uint32_t u = (uint32_t)f2bf(acc[hl][cf][2 * r2]) |
                     ((uint32_t)f2bf(acc[hl][cf][2 * r2 + 1]) << 16);
        *(uint32_t*)&part[outBase + c] = u;
      }
}

// ---------------- K6: fused tail — attproj+LN1+FFN1+FFN2+LN2+transposed output ----------------
__global__ __launch_bounds__(256) void k_tail(const unsigned short* __restrict__ part,
                                              const unsigned short* __restrict__ Wp,
                                              const float* __restrict__ bproj,
                                              const float* __restrict__ resid,
                                              const float* __restrict__ lg,
                                              const float* __restrict__ lb,
                                              const unsigned short* __restrict__ W1b,
                                              const float* __restrict__ b1,
                                              const unsigned short* __restrict__ W2b,
                                              const float* __restrict__ b2,
                                              float* __restrict__ out) {
  __shared__ __align__(16) unsigned short As[32 * 64];        // 4KB
  __shared__ __align__(16) char BsTt[33792];                  // 33KB (Bs staging / Tt union)
  __shared__ __align__(16) unsigned short As2[32 * 256];      // 16KB
  __shared__ __align__(16) unsigned short H1s[32 * 256];      // 16KB
  __shared__ float rsum[4][32][2];
  unsigned short* const Bs = (unsigned short*)BsTt;
  float(* const Tt)[33] = (float(*)[33])BsTt;
  const int tid = threadIdx.x, l = tid & 63, w = tid >> 6;
  const int g4 = l >> 4, ln = l & 15;
  const int m0 = blockIdx.x * 32;
  const int swz = (l & 7) ^ (l >> 3);

  // ---- phase 1: attproj GEMM (K=1024 over split partials) ----
  f32x4 acc[2][4] = {};
  for (int kt = 0; kt < 1024; kt += 64) {
    gload_lds16((const char*)part + (((size_t)(kt >> 9) * 8192 * 512) +
                                     (size_t)(m0 + w * 8 + (l >> 3)) * 512 +
                                     (kt & 511) + swz * 8) * 2,
                (char*)As + w * 1024);
#pragma unroll
    for (int j = 0; j < 8; ++j) {
      int seg = w * 8 + j;
      gload_lds16((const char*)Wp + ((size_t)(seg * 8 + (l >> 3)) * 1024 + kt + swz * 8) * 2,
                  (char*)Bs + seg * 1024);
    }
    __syncthreads();
#pragma unroll
    for (int kk = 0; kk < 2; ++kk) {
      short8 af[2], bfr[4];
#pragma unroll
      for (int fm = 0; fm < 2; ++fm)
        af[fm] = *(const short8*)((const char*)As + (fm * 16 + ln) * 128 +
                                  (((kk * 4 + g4) ^ (ln & 7)) * 16));
#pragma unroll
      for (int fn = 0; fn < 4; ++fn)
        bfr[fn] = *(const short8*)((const char*)Bs + (w * 64 + fn * 16 + ln) * 128 +
                                   (((kk * 4 + g4) ^ (ln & 7)) * 16));
#pragma unroll
      for (int fm = 0; fm < 2; ++fm)
#pragma unroll
        for (int fn = 0; fn < 4; ++fn)
          acc[fm][fn] = __builtin_amdgcn_mfma_f32_16x16x32_bf16(af[fm], bfr[fn], acc[fm][fn], 0, 0, 0);
    }
    __syncthreads();
  }

  // ---- LN1 stats (bias + resid) ----
  float vals[2][4][4];
#pragma unroll
  for (int fm = 0; fm < 2; ++fm)
#pragma unroll
    for (int r = 0; r < 4; ++r) {
      int row_l = fm * 16 + g4 * 4 + r;
      float s = 0.f, q = 0.f;
#pragma unroll
      for (int fn = 0; fn < 4; ++fn) {
        int col = w * 64 + fn * 16 + ln;
        float v = acc[fm][fn][r] + bproj[col] + resid[(size_t)(m0 + row_l) * 256 + col];
        vals[fm][fn][r] = v;
        s += v;
        q += v * v;
      }
#pragma unroll
      for (int o = 1; o < 16; o <<= 1) {
        s += __shfl_xor(s, o, 64);
        q += __shfl_xor(q, o, 64);
      }
      if (ln == 0) {
        rsum[w][row_l][0] = s;
        rsum[w][row_l][1] = q;
      }
    }
  __syncthreads();

  // ---- LN1: vals := addn (kept in regs) + As2 bf16 (chunk-swizzled) ----
#pragma unroll
  for (int fm = 0; fm < 2; ++fm)
#pragma unroll
    for (int r = 0; r < 4; ++r) {
      int row_l = fm * 16 + g4 * 4 + r;
      float s = rsum[0][row_l][0] + rsum[1][row_l][0] + rsum[2][row_l][0] + rsum[3][row_l][0];
      float q = rsum[0][row_l][1] + rsum[1][row_l][1] + rsum[2][row_l][1] + rsum[3][row_l][1];
      float mu = s * (1.0f / 256.0f);
      float rstd = rsqrtf(q * (1.0f / 256.0f) - mu * mu + 1e-5f);
#pragma unroll
      for (int fn = 0; fn < 4; ++fn) {
        int col = w * 64 + fn * 16 + ln;
        float o = (vals[fm][fn][r] - mu) * rstd * lg[col] + lb[col];
        vals[fm][fn][r] = o;  // addn, reused as FFN2 residual
        int slot = (col >> 3) ^ (row_l & 7);
        *(unsigned short*)((char*)As2 + row_l * 512 + slot * 16 + (col & 7) * 2) = f2bf(o);
      }
    }
  __syncthreads();

  // ---- phase 2: FFN1 h1 = leaky(As2 @ W1^T + b1) -> H1s (chunk-swizzled) ----
  f32x4 acc2[2][4] = {};
  for (int kt = 0; kt < 256; kt += 64) {
#pragma unroll
    for (int j = 0; j < 8; ++j) {
      int seg = w * 8 + j;
      gload_lds16((const char*)W1b + ((size_t)(seg * 8 + (l >> 3)) * 256 + kt + swz * 8) * 2,
                  (char*)Bs + seg * 1024);
    }
    __syncthreads();
#pragma unroll
    for (int kk = 0; kk < 2; ++kk) {
      short8 af[2], bfr[4];
#pragma unroll
      for (int fm = 0; fm < 2; ++fm) {
        int row = fm * 16 + ln;
        int chunk = (kt >> 3) + kk * 4 + g4;
        af[fm] = *(const short8*)((const char*)As2 + row * 512 + ((chunk ^ (row & 7)) * 16));
      }
#pragma unroll
      for (int fn = 0; fn < 4; ++fn)
        bfr[fn] = *(const short8*)((const char*)Bs + (w * 64 + fn * 16 + ln) * 128 +
                                   (((kk * 4 + g4) ^ (ln & 7)) * 16));
#pragma unroll
      for (int fm = 0; fm < 2; ++fm)
#pragma unroll
        for (int fn = 0; fn < 4; ++fn)
          acc2[fm][fn] = __builtin_amdgcn_mfma_f32_16x16x32_bf16(af[fm], bfr[fn], acc2[fm][fn], 0, 0, 0);
    }
    __syncthreads();
  }
#pragma unroll
  for (int fm = 0; fm < 2; ++fm)
#pragma unroll
    for (int fn = 0; fn < 4; ++fn)
#pragma unroll
      for (int r = 0; r < 4; ++r) {
        int row_l = fm * 16 + g4 * 4 + r;
        int col = w * 64 + fn * 16 + ln;
        float v = acc2[fm][fn][r] + b1[col];
        v = (v > 0.f) ? v : 0.1f * v;
        int slot = (col >> 3) ^ (row_l & 7);
        *(unsigned short*)((char*)H1s + row_l * 512 + slot * 16 + (col & 7) * 2) = f2bf(v);
      }
  __syncthreads();

  // ---- phase 3: FFN2 h2 = H1s @ W2^T + b2 + addn(regs); LN2 -> Tt -> transposed out ----
  f32x4 acc3[2][4] = {};
  for (int kt = 0; kt < 256; kt += 64) {
#pragma unroll
    for (int j = 0; j < 8; ++j) {
      int seg = w * 8 + j;
      gload_lds16((const char*)W2b + ((size_t)(seg * 8 + (l >> 3)) * 256 + kt + swz * 8) * 2,
                  (char*)Bs + seg * 1024);
    }
    __syncthreads();
#pragma unroll
    for (int kk = 0; kk < 2; ++kk) {
      short8 af[2], bfr[4];
#pragma unroll
      for (int fm = 0; fm < 2; ++fm) {
        int row = fm * 16 + ln;
        int chunk = (kt >> 3) + kk * 4 + g4;
        af[fm] = *(const short8*)((const char*)H1s + row * 512 + ((chunk ^ (row & 7)) * 16));
      }
#pragma unroll
      for (int fn = 0; fn < 4; ++fn)
        bfr[fn] = *(const short8*)((const char*)Bs + (w * 64 + fn * 16 + ln) * 128 +
                                   (((kk * 4 + g4) ^ (ln & 7)) * 16));
#pragma unroll
      for (int fm = 0; fm < 2; ++fm)
#pragma unroll
        for (int fn = 0; fn < 4; ++fn)
          acc3[fm][fn] = __builtin_amdgcn_mfma_f32_16x16x32_bf16(af[fm], bfr[fn], acc3[fm][fn], 0, 0, 0);
    }
    __syncthreads();
  }

  // h2 = acc3 + b2 + addn; LN2 stats
#pragma unroll
  for (int fm = 0; fm < 2; ++fm)
#pragma unroll
    for (int r = 0; r < 4; ++r) {
      int row_l = fm * 16 + g4 * 4 + r;
      float s = 0.f, q = 0.f;
#pragma unroll
      for (int fn = 0; fn < 4; ++fn) {
        int col = w * 64 + fn * 16 + ln;
        float v = acc3[fm][fn][r] + b2[col] + vals[fm][fn][r];
        vals[fm][fn][r] = v;
        s += v;
        q += v * v;
      }
#pragma unroll
      for (int o = 1; o < 16; o <<= 1) {
        s += __shfl_xor(s, o, 64);
        q += __shfl_xor(q, o, 64);
      }
      if (ln == 0) {
        rsum[w][row_l][0] = s;
        rsum[w][row_l][1] = q;
      }
    }
  __syncthreads();  // also drains last Bs reads before Tt overwrites the union

#pragma unroll
  for (int fm = 0; fm < 2; ++fm)
#pragma unroll
    for (int r = 0; r < 4; ++r) {
      int row_l = fm * 16 + g4 * 4 + r;
      float s = rsum[0][row_l][0] + rsum[1][row_l][0] + rsum[2][row_l][0] + rsum[3][row_l][0];
      float q = rsum[0][row_l][1] + rsum[1][row_l][1] + rsum[2][row_l][1] + rsum[3][row_l][1];
      float mu = s * (1.0f / 256.0f);
      float rstd = rsqrtf(q * (1.0f / 256.0f) - mu * mu + 1e-5f);
#pragma unroll
      for (int fn = 0; fn < 4; ++fn) {
        int col = w * 64 + fn * 16 + ln;
        Tt[col][row_l] = (vals[fm][fn][r] - mu) * rstd * lg[col] + lb[col];
      }
    }
  __syncthreads();

  const int bimg = m0 >> 10, nn0 = m0 & 1023;
#pragma unroll
  for (int i = 0; i < 8; ++i) {
    int c = i * 32 + (tid >> 3);
    int ng = (tid & 7) * 4;
    float4 o = make_float4(Tt[c][ng], Tt[c][ng + 1], Tt[c][ng + 2], Tt[c][ng + 3]);
    *(float4*)&out[((size_t)bimg * 256 + c) * 1024 + nn0 + ng] = o;
  }
}

// ---------------- host launcher ----------------
extern "C" void kernel_launch(void* const* d_in, const int* in_sizes, int n_in,
                              void* d_out, int out_size, void* d_ws, size_t ws_size,
                              hipStream_t stream) {
  const float* x     = (const float*)d_in[0];
  const float* Wk    = (const float*)d_in[1];
  const float* bk    = (const float*)d_in[2];
  const float* Wq    = (const float*)d_in[3];
  const float* bq    = (const float*)d_in[4];
  const float* Wv    = (const float*)d_in[5];
  const float* bv    = (const float*)d_in[6];
  const float* Wproj = (const float*)d_in[7];
  const float* bproj = (const float*)d_in[8];
  const float* ln_g  = (const float*)d_in[9];
  const float* ln_b  = (const float*)d_in[10];
  const float* W1    = (const float*)d_in[11];
  const float* b1    = (const float*)d_in[12];
  const float* W2    = (const float*)d_in[13];
  const float* b2    = (const float*)d_in[14];

  char* ws = (char*)d_ws;
  constexpr size_t OFF_XPTB  = 0;                                    // bf16 [8192][256]
  constexpr size_t OFF_XPTF  = OFF_XPTB  + (size_t)8192 * 256 * 2;   // f32  [8192][256]
  constexpr size_t OFF_WPACK = OFF_XPTF  + (size_t)8192 * 256 * 4;   // bf16 [1536][2304]
  constexpr size_t OFF_BIAS  = OFF_WPACK + (size_t)1536 * 2304 * 2;  // f32  [1536]
  constexpr size_t OFF_WPROJ = OFF_BIAS  + (size_t)1536 * 4;         // bf16 [256][1024] (dup K)
  constexpr size_t OFF_W1B   = OFF_WPROJ + (size_t)256 * 1024 * 2;   // bf16 [256][256]
  constexpr size_t OFF_W2B   = OFF_W1B   + (size_t)256 * 256 * 2;    // bf16 [256][256]
  constexpr size_t OFF_PET   = OFF_W2B   + (size_t)256 * 256 * 2;    // f32  [256][32]
  constexpr size_t OFF_ZERO  = OFF_PET   + (size_t)256 * 32 * 4;     // f32  [256] zeros (1KB)
  constexpr size_t OFF_KQV   = OFF_ZERO  + 1024;                     // bf16 [8192][1536]
  constexpr size_t OFF_PART  = OFF_KQV   + (size_t)8192 * 1536 * 2;  // bf16 [2][8192][512]

  (void)in_sizes; (void)n_in; (void)out_size; (void)ws_size;

  const char* zp = (const char*)(ws + OFF_ZERO);

  k_prep<<<14337, 256, 0, stream>>>(Wk, Wq, Wv, bk, bq, bv, Wproj, W1, W2,
                                    (unsigned short*)(ws + OFF_WPACK),
                                    (float*)(ws + OFF_BIAS),
                                    (unsigned short*)(ws + OFF_WPROJ),
                                    (unsigned short*)(ws + OFF_W1B),
                                    (unsigned short*)(ws + OFF_W2B),
                                    (float*)(ws + OFF_PET), (float*)(ws + OFF_ZERO));
  k_xpt<<<dim3(8, 32, 8), 256, 0, stream>>>(x, (const float*)(ws + OFF_PET),
                                            (unsigned short*)(ws + OFF_XPTB),
                                            (float*)(ws + OFF_XPTF));
  // merged conv K+Q+V -> kqv[8192][1536]
  k_gemm_conv<<<dim3(64, 8), 256, 0, stream>>>(
      (const unsigned short*)(ws + OFF_XPTB), (const unsigned short*)(ws + OFF_WPACK),
      (unsigned short*)(ws + OFF_KQV), (const float*)(ws + OFF_BIAS), zp);
  // fused attention -> partials [2][8192][512]
  k_attn<<<dim3(512), 512, 0, stream>>>((const unsigned short*)(ws + OFF_KQV),
                                        (unsigned short*)(ws + OFF_PART));
  // fused tail: attproj + LN1 + FFN1 + FFN2 + LN2 + transposed output
  k_tail<<<256, 256, 0, stream>>>((const unsigned short*)(ws + OFF_PART),
                                  (const unsigned short*)(ws + OFF_WPROJ), bproj,
                                  (const float*)(ws + OFF_XPTF), ln_g, ln_b,
                                  (const unsigned short*)(ws + OFF_W1B), b1,
                                  (const unsigned short*)(ws + OFF_W2B), b2,
                                  (float*)d_out);
}